// Round 1
// baseline (2564.904 us; speedup 1.0000x reference)
//
#include <hip/hip_runtime.h>

#define B_    16
#define T_    8192
#define D_    512
#define K_    8192
#define S_    1024
#define N_    16384      // B_*S_
#define NBT   131072     // B_*T_

// d_out float offsets
#define LOSS_OFF 67108864
#define IDX_OFF  67108865
#define BND_OFF  67239937

__device__ __forceinline__ unsigned int fsort(float f){
  unsigned int u = __float_as_uint(f);
  return (u & 0x80000000u) ? ~u : (u | 0x80000000u);
}
__device__ __forceinline__ float funsort(unsigned int su){
  unsigned int u = (su & 0x80000000u) ? (su ^ 0x80000000u) : ~su;
  return __uint_as_float(u);
}
__device__ __forceinline__ unsigned long long umin64(unsigned long long a, unsigned long long b){
  return a < b ? a : b;
}

__global__ void k_init(int* cnt){
  if(threadIdx.x == 0 && blockIdx.x == 0) *cnt = 0;
}

// |emb_k|^2, one wave per codebook row
__global__ void k_embnorm(const float4* __restrict__ emb4, float* __restrict__ enorm){
  const int wid  = (blockIdx.x * blockDim.x + threadIdx.x) >> 6;   // 0..8191
  const int lane = threadIdx.x & 63;
  float4 a = emb4[wid * 128 + (lane << 1)];
  float4 b = emb4[wid * 128 + (lane << 1) + 1];
  float s = a.x*a.x + a.y*a.y + a.z*a.z + a.w*a.w
          + b.x*b.x + b.y*b.y + b.z*b.z + b.w*b.w;
  #pragma unroll
  for(int off = 32; off; off >>= 1) s += __shfl_xor(s, off);
  if(lane == 0) enorm[wid] = s;
}

// boundary logits in fp64 (sign decision robustness); per-block count -> atomic
__global__ void k_boundary(const float4* __restrict__ x4, const float4* __restrict__ wb4,
                           const float* __restrict__ bb, float* __restrict__ bnd,
                           int* __restrict__ cnt){
  const int lane = threadIdx.x & 63, wv = threadIdx.x >> 6;
  const int wg = (blockIdx.x << 2) + wv;         // 0..4095, 32 rows each
  const float4 w0 = wb4[lane << 1], w1 = wb4[(lane << 1) + 1];
  const double bbv = (double)bb[0];
  int c = 0;
  const int rbase = wg << 5;
  for(int r = 0; r < 32; r++){
    const int row = rbase + r;
    float4 a = x4[row * 128 + (lane << 1)];
    float4 b = x4[row * 128 + (lane << 1) + 1];
    double s = (double)a.x*w0.x + (double)a.y*w0.y + (double)a.z*w0.z + (double)a.w*w0.w
             + (double)b.x*w1.x + (double)b.y*w1.y + (double)b.z*w1.z + (double)b.w*w1.w;
    #pragma unroll
    for(int off = 32; off; off >>= 1) s += __shfl_xor(s, off);
    const bool f = (s + bbv) > 0.0;
    if(lane == 0){ bnd[row] = f ? 1.0f : 0.0f; c += (int)f; }
  }
  __shared__ int sc[4];
  if(lane == 0) sc[wv] = c;
  __syncthreads();
  if(threadIdx.x == 0) atomicAdd(cnt, sc[0] + sc[1] + sc[2] + sc[3]);
}

// mean-pool over SPAN=8; sequential t order (matches ref rounding closely)
__global__ void k_pool(const float4* __restrict__ x4, float4* __restrict__ pooled4){
  const int u = blockIdx.x * 256 + threadIdx.x;   // 0..2097151
  const int row = u >> 7, c4 = u & 127;
  const int b = row >> 10, s = row & 1023;
  const float4* src = x4 + ((size_t)(b * T_ + (s << 3)) * 128 + c4);
  float4 acc = src[0];
  #pragma unroll
  for(int t = 1; t < 8; t++){
    float4 v = src[(size_t)t * 128];
    acc.x += v.x; acc.y += v.y; acc.z += v.z; acc.w += v.w;
  }
  acc.x *= 0.125f; acc.y *= 0.125f; acc.z *= 0.125f; acc.w *= 0.125f;
  pooled4[u] = acc;
}

// fp32 distance GEMM: 64x64 tile, 4x4 micro-tile; emits top-2 (dist,idx) per (row, 64-col block)
__launch_bounds__(256)
__global__ void k_dist(const float* __restrict__ pooled, const float* __restrict__ emb,
                       const float* __restrict__ enorm, unsigned long long* __restrict__ cand2){
  __shared__ float smem[4096];                      // 16 KB
  float (*sA)[64] = (float(*)[64])smem;             // [k][m]
  float (*sB)[64] = (float(*)[64])(smem + 2048);    // [k][n]
  const int tid = threadIdx.x;
  const int tx = tid & 15, ty = tid >> 4;
  const int rowbase = blockIdx.y << 6, colbase = blockIdx.x << 6;
  float acc[4][4];
  #pragma unroll
  for(int i = 0; i < 4; i++)
    #pragma unroll
    for(int j = 0; j < 4; j++) acc[i][j] = 0.f;

  const int m0 = tid >> 3, k40 = tid & 7;
  for(int kb = 0; kb < 512; kb += 32){
    #pragma unroll
    for(int h = 0; h < 2; h++){
      const int m = m0 + (h << 5);
      const float4 av = *(const float4*)(pooled + (size_t)(rowbase + m) * 512 + kb + (k40 << 2));
      const float4 bv = *(const float4*)(emb    + (size_t)(colbase + m) * 512 + kb + (k40 << 2));
      const int kk = k40 << 2;
      sA[kk+0][m] = av.x; sA[kk+1][m] = av.y; sA[kk+2][m] = av.z; sA[kk+3][m] = av.w;
      sB[kk+0][m] = bv.x; sB[kk+1][m] = bv.y; sB[kk+2][m] = bv.z; sB[kk+3][m] = bv.w;
    }
    __syncthreads();
    #pragma unroll
    for(int k = 0; k < 32; k++){
      const float4 a = *(const float4*)&sA[k][ty << 2];
      const float4 b = *(const float4*)&sB[k][tx << 2];
      acc[0][0] = fmaf(a.x, b.x, acc[0][0]); acc[0][1] = fmaf(a.x, b.y, acc[0][1]);
      acc[0][2] = fmaf(a.x, b.z, acc[0][2]); acc[0][3] = fmaf(a.x, b.w, acc[0][3]);
      acc[1][0] = fmaf(a.y, b.x, acc[1][0]); acc[1][1] = fmaf(a.y, b.y, acc[1][1]);
      acc[1][2] = fmaf(a.y, b.z, acc[1][2]); acc[1][3] = fmaf(a.y, b.w, acc[1][3]);
      acc[2][0] = fmaf(a.z, b.x, acc[2][0]); acc[2][1] = fmaf(a.z, b.y, acc[2][1]);
      acc[2][2] = fmaf(a.z, b.z, acc[2][2]); acc[2][3] = fmaf(a.z, b.w, acc[2][3]);
      acc[3][0] = fmaf(a.w, b.x, acc[3][0]); acc[3][1] = fmaf(a.w, b.y, acc[3][1]);
      acc[3][2] = fmaf(a.w, b.z, acc[3][2]); acc[3][3] = fmaf(a.w, b.w, acc[3][3]);
    }
    __syncthreads();
  }

  // epilogue: top-2 per row within this 64-col block (union of per-thread top-2s)
  unsigned long long* c2 = (unsigned long long*)smem;   // [64][32]
  #pragma unroll
  for(int i = 0; i < 4; i++){
    const int rl = (ty << 2) + i;
    unsigned long long k1 = ~0ull, k2 = ~0ull;
    #pragma unroll
    for(int j = 0; j < 4; j++){
      const int col = colbase + (tx << 2) + j;
      const float d = enorm[col] - 2.0f * acc[i][j];
      const unsigned long long key = ((unsigned long long)fsort(d) << 32) | (unsigned int)col;
      if(key < k1){ k2 = k1; k1 = key; } else if(key < k2){ k2 = key; }
    }
    c2[(rl << 5) + (tx << 1)]     = k1;
    c2[(rl << 5) + (tx << 1) + 1] = k2;
  }
  __syncthreads();
  if(tid < 64){
    unsigned long long k1 = ~0ull, k2 = ~0ull;
    const unsigned long long* p = c2 + (tid << 5);
    #pragma unroll
    for(int t = 0; t < 32; t++){
      const unsigned long long v = p[t];
      if(v < k1){ k2 = k1; k1 = v; } else if(v < k2){ k2 = v; }
    }
    unsigned long long* o = cand2 + (((size_t)(rowbase + tid) << 7) + blockIdx.x) * 2;
    o[0] = k1; o[1] = k2;
  }
}

// fp64 rescore of all candidates within margin of the fp32 min -> exact argmin + per-row loss term
__launch_bounds__(256)
__global__ void k_fixup(const float* __restrict__ pooled, const float* __restrict__ emb,
                        const unsigned long long* __restrict__ cand2,
                        int* __restrict__ idxf, double* __restrict__ part){
  const int lane = threadIdx.x & 63, wv = threadIdx.x >> 6;
  const int row = (blockIdx.x << 2) + wv;
  const unsigned long long* cr = cand2 + ((size_t)row << 8);
  unsigned long long ks[4];
  ks[0] = cr[lane]; ks[1] = cr[lane + 64]; ks[2] = cr[lane + 128]; ks[3] = cr[lane + 192];
  unsigned long long mn = umin64(umin64(ks[0], ks[1]), umin64(ks[2], ks[3]));
  #pragma unroll
  for(int off = 32; off; off >>= 1) mn = umin64(mn, __shfl_xor(mn, off));
  const float thr = funsort((unsigned int)(mn >> 32)) + 1e-3f;

  double bestd = 1e300; int besti = 0x7fffffff;
  const float4* p4 = (const float4*)(pooled + ((size_t)row << 9));
  const float4 pa = p4[lane << 1], pb = p4[(lane << 1) + 1];
  for(int g = 0; g < 4; g++){
    const bool flag = funsort((unsigned int)(ks[g] >> 32)) <= thr;
    unsigned long long mask = __ballot(flag);
    while(mask){
      const int l = __ffsll((unsigned long long)mask) - 1;
      mask &= mask - 1;
      const unsigned long long key = __shfl(ks[g], l);
      const int code = (int)(key & 0xffffffffu);
      const float4* e4 = (const float4*)(emb + ((size_t)code << 9));
      const float4 ea = e4[lane << 1], eb = e4[(lane << 1) + 1];
      double s = 0.0, d;
      d = (double)pa.x - ea.x; s += d * d;  d = (double)pa.y - ea.y; s += d * d;
      d = (double)pa.z - ea.z; s += d * d;  d = (double)pa.w - ea.w; s += d * d;
      d = (double)pb.x - eb.x; s += d * d;  d = (double)pb.y - eb.y; s += d * d;
      d = (double)pb.z - eb.z; s += d * d;  d = (double)pb.w - eb.w; s += d * d;
      #pragma unroll
      for(int off = 32; off; off >>= 1) s += __shfl_xor(s, off);
      if(s < bestd || (s == bestd && code < besti)){ bestd = s; besti = code; }
    }
  }
  __shared__ double se[4];
  if(lane == 0){ idxf[row] = besti; se[wv] = bestd; }
  __syncthreads();
  if(threadIdx.x == 0) part[blockIdx.x] = se[0] + se[1] + se[2] + se[3];
}

__global__ void k_loss(const double* __restrict__ part, const int* __restrict__ cnt,
                       float* __restrict__ out_loss){
  const int tid = threadIdx.x;
  double s = 0.0;
  for(int i = tid; i < 4096; i += 256) s += part[i];
  #pragma unroll
  for(int off = 32; off; off >>= 1) s += __shfl_xor(s, off);
  __shared__ double sb[4];
  if((tid & 63) == 0) sb[tid >> 6] = s;
  __syncthreads();
  if(tid == 0){
    const double e  = sb[0] + sb[1] + sb[2] + sb[3];
    const double el = e / (double)((size_t)N_ * 512);
    const double bm = (double)(*cnt) / 131072.0 - 0.125;
    const double loss = 0.25 * el + 0.01 * bm * bm;
    *out_loss = (float)loss;
  }
}

// expand codes over SPAN, write quantized_out + idx_out
__global__ void k_expand(const float4* __restrict__ emb4, const int* __restrict__ idxf,
                         float4* __restrict__ q4, float* __restrict__ idxo){
  const int u = blockIdx.x * 256 + threadIdx.x;   // 0..16777215
  const int rt = u >> 7, c4 = u & 127;
  const int seg = rt >> 3;
  const int idx = idxf[seg];
  q4[u] = emb4[idx * 128 + c4];
  if(c4 == 0) idxo[rt] = (float)idx;
}

extern "C" void kernel_launch(void* const* d_in, const int* in_sizes, int n_in,
                              void* d_out, int out_size, void* d_ws, size_t ws_size,
                              hipStream_t stream){
  const float* x   = (const float*)d_in[0];
  const float* emb = (const float*)d_in[1];
  const float* wb  = (const float*)d_in[2];
  const float* bb  = (const float*)d_in[3];
  float* out = (float*)d_out;

  // small workspace fields
  char* ws = (char*)d_ws;
  int*    cnt   = (int*)(ws + 0);
  double* part  = (double*)(ws + 64);       // 4096 doubles
  float*  enorm = (float*)(ws + 32832);     // 8192 floats
  int*    idxf  = (int*)(ws + 65600);       // 16384 ints

  // big scratch inside the quantized_out region (overwritten last by k_expand)
  float* pooled = (float*)d_out;                                        // 32 MB
  unsigned long long* cand2 = (unsigned long long*)((char*)d_out + (48ull << 20)); // 32 MB

  float* bnd   = out + BND_OFF;
  float* idxo  = out + IDX_OFF;
  float* lossp = out + LOSS_OFF;

  hipLaunchKernelGGL(k_init,     dim3(1),         dim3(64),  0, stream, cnt);
  hipLaunchKernelGGL(k_embnorm,  dim3(2048),      dim3(256), 0, stream, (const float4*)emb, enorm);
  hipLaunchKernelGGL(k_boundary, dim3(1024),      dim3(256), 0, stream, (const float4*)x, (const float4*)wb, bb, bnd, cnt);
  hipLaunchKernelGGL(k_pool,     dim3(8192),      dim3(256), 0, stream, (const float4*)x, (float4*)pooled);
  hipLaunchKernelGGL(k_dist,     dim3(128, 256),  dim3(256), 0, stream, pooled, emb, enorm, cand2);
  hipLaunchKernelGGL(k_fixup,    dim3(4096),      dim3(256), 0, stream, pooled, emb, cand2, idxf, part);
  hipLaunchKernelGGL(k_loss,     dim3(1),         dim3(256), 0, stream, part, cnt, lossp);
  hipLaunchKernelGGL(k_expand,   dim3(65536),     dim3(256), 0, stream, (const float4*)emb, idxf, (float4*)d_out, idxo);
}

// Round 2
// 750.319 us; speedup vs baseline: 3.4184x; 3.4184x over previous
//
#include <hip/hip_runtime.h>

#define B_    16
#define T_    8192
#define D_    512
#define K_    8192
#define S_    1024
#define N_    16384      // B_*S_
#define NBT   131072     // B_*T_

// d_out float offsets
#define LOSS_OFF 67108864
#define IDX_OFF  67108865
#define BND_OFF  67239937

typedef __bf16 bf16x8 __attribute__((ext_vector_type(8)));
typedef float  f32x4  __attribute__((ext_vector_type(4)));

__device__ __forceinline__ unsigned int fsort(float f){
  unsigned int u = __float_as_uint(f);
  return (u & 0x80000000u) ? ~u : (u | 0x80000000u);
}
__device__ __forceinline__ float funsort(unsigned int su){
  unsigned int u = (su & 0x80000000u) ? (su ^ 0x80000000u) : ~su;
  return __uint_as_float(u);
}
__device__ __forceinline__ unsigned short f2bf(float f){
  unsigned int u = __float_as_uint(f);
  return (unsigned short)((u + 0x7fffu + ((u >> 16) & 1u)) >> 16);
}
__device__ __forceinline__ void gload16(const void* g, void* l){
  __builtin_amdgcn_global_load_lds((const __attribute__((address_space(1))) void*)g,
                                   (__attribute__((address_space(3))) void*)l, 16, 0, 0);
}

__global__ void k_init(int* cnt){
  if(threadIdx.x == 0 && blockIdx.x == 0) *cnt = 0;
}

// |emb_k|^2 (one wave per codebook row) + bf16 copy of emb
__global__ void k_embnorm(const float4* __restrict__ emb4, float* __restrict__ enorm,
                          unsigned short* __restrict__ embh){
  const int wid  = (blockIdx.x * blockDim.x + threadIdx.x) >> 6;   // 0..8191
  const int lane = threadIdx.x & 63;
  float4 a = emb4[wid * 128 + (lane << 1)];
  float4 b = emb4[wid * 128 + (lane << 1) + 1];
  float s = a.x*a.x + a.y*a.y + a.z*a.z + a.w*a.w
          + b.x*b.x + b.y*b.y + b.z*b.z + b.w*b.w;
  #pragma unroll
  for(int off = 32; off; off >>= 1) s += __shfl_xor(s, off);
  if(lane == 0) enorm[wid] = s;
  unsigned short* dst = embh + ((size_t)wid << 9) + (lane << 3);
  *(ushort4*)(dst)     = make_ushort4(f2bf(a.x), f2bf(a.y), f2bf(a.z), f2bf(a.w));
  *(ushort4*)(dst + 4) = make_ushort4(f2bf(b.x), f2bf(b.y), f2bf(b.z), f2bf(b.w));
}

// boundary logits in fp64 (sign decision robustness); per-block count -> atomic
__global__ void k_boundary(const float4* __restrict__ x4, const float4* __restrict__ wb4,
                           const float* __restrict__ bb, float* __restrict__ bnd,
                           int* __restrict__ cnt){
  const int lane = threadIdx.x & 63, wv = threadIdx.x >> 6;
  const int wg = (blockIdx.x << 2) + wv;         // 0..4095, 32 rows each
  const float4 w0 = wb4[lane << 1], w1 = wb4[(lane << 1) + 1];
  const double bbv = (double)bb[0];
  int c = 0;
  const int rbase = wg << 5;
  for(int r = 0; r < 32; r++){
    const int row = rbase + r;
    float4 a = x4[row * 128 + (lane << 1)];
    float4 b = x4[row * 128 + (lane << 1) + 1];
    double s = (double)a.x*w0.x + (double)a.y*w0.y + (double)a.z*w0.z + (double)a.w*w0.w
             + (double)b.x*w1.x + (double)b.y*w1.y + (double)b.z*w1.z + (double)b.w*w1.w;
    #pragma unroll
    for(int off = 32; off; off >>= 1) s += __shfl_xor(s, off);
    const bool f = (s + bbv) > 0.0;
    if(lane == 0){ bnd[row] = f ? 1.0f : 0.0f; c += (int)f; }
  }
  __shared__ int sc[4];
  if(lane == 0) sc[wv] = c;
  __syncthreads();
  if(threadIdx.x == 0) atomicAdd(cnt, sc[0] + sc[1] + sc[2] + sc[3]);
}

// mean-pool over SPAN=8 (sequential t order, fp32) + bf16 copy
__global__ void k_pool(const float4* __restrict__ x4, float4* __restrict__ pooled4,
                       unsigned short* __restrict__ pooledh){
  const int u = blockIdx.x * 256 + threadIdx.x;   // 0..2097151
  const int row = u >> 7, c4 = u & 127;
  const int b = row >> 10, s = row & 1023;
  const float4* src = x4 + ((size_t)(b * T_ + (s << 3)) * 128 + c4);
  float4 acc = src[0];
  #pragma unroll
  for(int t = 1; t < 8; t++){
    float4 v = src[(size_t)t * 128];
    acc.x += v.x; acc.y += v.y; acc.z += v.z; acc.w += v.w;
  }
  acc.x *= 0.125f; acc.y *= 0.125f; acc.z *= 0.125f; acc.w *= 0.125f;
  pooled4[u] = acc;
  *(ushort4*)(pooledh + ((size_t)u << 2)) =
      make_ushort4(f2bf(acc.x), f2bf(acc.y), f2bf(acc.z), f2bf(acc.w));
}

// bf16 MFMA distance GEMM: 128x128 tile, BK=32, global_load_lds staging.
// Emits top-2 packed keys (19-bit trunc sorted dist | 13-bit col) per (row, 128-col tile).
__launch_bounds__(256, 2)
__global__ void k_distx(const unsigned short* __restrict__ Ah,
                        const unsigned short* __restrict__ Bh,
                        const float* __restrict__ enorm,
                        unsigned int* __restrict__ cand){
  __shared__ __align__(16) unsigned short sA[4096];   // [128][32] bf16
  __shared__ __align__(16) unsigned short sB[4096];
  const int tid  = threadIdx.x;
  const int w    = tid >> 6, lane = tid & 63;
  const int wm   = w >> 1,  wn   = w & 1;
  const int c    = lane & 15, q  = lane >> 4;

  // supertile: 8 row-tiles x 64 col-tiles per 512-block group (L2/LLC locality)
  const int bid   = blockIdx.x;
  const int st    = bid >> 9;
  const int loc   = bid & 511;
  const int row_t = (st << 3) + (loc & 7);   // 0..127
  const int col_t = loc >> 3;                // 0..63
  const int rowbase = row_t << 7;
  const int colbase = col_t << 7;

  f32x4 acc[4][4];
  #pragma unroll
  for(int i = 0; i < 4; i++)
    #pragma unroll
    for(int j = 0; j < 4; j++) acc[i][j] = (f32x4){0.f, 0.f, 0.f, 0.f};

  const int sr  = lane >> 2;            // staging row within 16-row chunk
  const int skc = (lane & 3) << 3;      // staging k offset (elements)

  const unsigned short* Ap0 = Ah + (size_t)(rowbase + w*32 + sr)      * 512 + skc;
  const unsigned short* Ap1 = Ah + (size_t)(rowbase + w*32 + 16 + sr) * 512 + skc;
  const unsigned short* Bp0 = Bh + (size_t)(colbase + w*32 + sr)      * 512 + skc;
  const unsigned short* Bp1 = Bh + (size_t)(colbase + w*32 + 16 + sr) * 512 + skc;
  unsigned short* lA0 = &sA[(w*32)      * 32];
  unsigned short* lA1 = &sA[(w*32 + 16) * 32];
  unsigned short* lB0 = &sB[(w*32)      * 32];
  unsigned short* lB1 = &sB[(w*32 + 16) * 32];

  for(int kb = 0; kb < 512; kb += 32){
    gload16(Ap0 + kb, lA0);
    gload16(Ap1 + kb, lA1);
    gload16(Bp0 + kb, lB0);
    gload16(Bp1 + kb, lB1);
    __syncthreads();
    bf16x8 af[4], bg[4];
    #pragma unroll
    for(int i = 0; i < 4; i++) af[i] = *(const bf16x8*)&sA[(wm*64 + i*16 + c)*32 + q*8];
    #pragma unroll
    for(int j = 0; j < 4; j++) bg[j] = *(const bf16x8*)&sB[(wn*64 + j*16 + c)*32 + q*8];
    #pragma unroll
    for(int i = 0; i < 4; i++)
      #pragma unroll
      for(int j = 0; j < 4; j++)
        acc[i][j] = __builtin_amdgcn_mfma_f32_16x16x32_bf16(af[i], bg[j], acc[i][j], 0, 0, 0);
    __syncthreads();
  }

  // epilogue: dist = enorm - 2*dot; top-2 per row over this wave's 64 cols,
  // then the two waves sharing rows write disjoint tile slots? No: waves wn=0/1
  // cover different col halves of the SAME rows -> reduce per 64, write per-wave half-tile.
  float en[4];
  #pragma unroll
  for(int j = 0; j < 4; j++) en[j] = enorm[colbase + wn*64 + j*16 + c];

  #pragma unroll
  for(int i = 0; i < 4; i++){
    #pragma unroll
    for(int r = 0; r < 4; r++){
      unsigned int k1 = 0xffffffffu, k2 = 0xffffffffu;
      #pragma unroll
      for(int j = 0; j < 4; j++){
        const float d = fmaf(-2.0f, acc[i][j][r], en[j]);
        const unsigned int col = (unsigned int)(colbase + wn*64 + j*16 + c);
        const unsigned int key = (fsort(d) & 0xffffe000u) | col;
        if(key < k1){ k2 = k1; k1 = key; } else if(key < k2){ k2 = key; }
      }
      #pragma unroll
      for(int off = 1; off < 16; off <<= 1){
        const unsigned int o1 = __shfl_xor(k1, off);
        const unsigned int o2 = __shfl_xor(k2, off);
        if(o1 < k1){ k2 = min(k1, o2); k1 = o1; }
        else       { k2 = min(k2, o1); }
      }
      if(c == 0){
        const int row = rowbase + wm*64 + i*16 + (q << 2) + r;
        // 2 slots per (tile, wave-half): 4 u32 per (row, col-tile)
        unsigned int* o = cand + (((size_t)row << 8) + (col_t << 2) + (wn << 1));
        o[0] = k1; o[1] = k2;
      }
    }
  }
}

// fp64 rescore of candidates within margin of min -> exact argmin + per-row loss term
__launch_bounds__(256)
__global__ void k_fixup(const float* __restrict__ pooled, const float* __restrict__ emb,
                        const unsigned int* __restrict__ cand,
                        int* __restrict__ idxf, double* __restrict__ part){
  const int lane = threadIdx.x & 63, wv = threadIdx.x >> 6;
  const int row = (blockIdx.x << 2) + wv;
  const unsigned int* cr = cand + ((size_t)row << 8);
  unsigned int ks[4];
  ks[0] = cr[lane]; ks[1] = cr[lane + 64]; ks[2] = cr[lane + 128]; ks[3] = cr[lane + 192];
  unsigned int mn = min(min(ks[0], ks[1]), min(ks[2], ks[3]));
  #pragma unroll
  for(int off = 32; off; off >>= 1) mn = min(mn, (unsigned int)__shfl_xor(mn, off));
  const float thr = funsort(mn & 0xffffe000u) + 0.01f;   // covers bf16 + key-trunc error

  double bestd = 1e300; int besti = 0x7fffffff;
  const float4* p4 = (const float4*)(pooled + ((size_t)row << 9));
  const float4 pa = p4[lane << 1], pb = p4[(lane << 1) + 1];
  #pragma unroll
  for(int g = 0; g < 4; g++){
    const bool flag = funsort(ks[g] & 0xffffe000u) <= thr;
    unsigned long long mask = __ballot(flag);
    while(mask){
      const int l = __ffsll(mask) - 1;
      mask &= mask - 1;
      const int code = (int)(__shfl(ks[g], l) & 0x1fffu);
      const float4* e4 = (const float4*)(emb + ((size_t)code << 9));
      const float4 ea = e4[lane << 1], eb = e4[(lane << 1) + 1];
      double s = 0.0, d;
      d = (double)pa.x - ea.x; s += d * d;  d = (double)pa.y - ea.y; s += d * d;
      d = (double)pa.z - ea.z; s += d * d;  d = (double)pa.w - ea.w; s += d * d;
      d = (double)pb.x - eb.x; s += d * d;  d = (double)pb.y - eb.y; s += d * d;
      d = (double)pb.z - eb.z; s += d * d;  d = (double)pb.w - eb.w; s += d * d;
      #pragma unroll
      for(int off = 32; off; off >>= 1) s += __shfl_xor(s, off);
      if(s < bestd || (s == bestd && code < besti)){ bestd = s; besti = code; }
    }
  }
  __shared__ double se[4];
  if(lane == 0){ idxf[row] = besti; se[wv] = bestd; }
  __syncthreads();
  if(threadIdx.x == 0) part[blockIdx.x] = se[0] + se[1] + se[2] + se[3];
}

__global__ void k_loss(const double* __restrict__ part, const int* __restrict__ cnt,
                       float* __restrict__ out_loss){
  const int tid = threadIdx.x;
  double s = 0.0;
  for(int i = tid; i < 4096; i += 256) s += part[i];
  #pragma unroll
  for(int off = 32; off; off >>= 1) s += __shfl_xor(s, off);
  __shared__ double sb[4];
  if((tid & 63) == 0) sb[tid >> 6] = s;
  __syncthreads();
  if(tid == 0){
    const double e  = sb[0] + sb[1] + sb[2] + sb[3];
    const double el = e / (double)((size_t)N_ * 512);
    const double bm = (double)(*cnt) / 131072.0 - 0.125;
    const double loss = 0.25 * el + 0.01 * bm * bm;
    *out_loss = (float)loss;
  }
}

// expand codes over SPAN, write quantized_out + idx_out
__global__ void k_expand(const float4* __restrict__ emb4, const int* __restrict__ idxf,
                         float4* __restrict__ q4, float* __restrict__ idxo){
  const int u = blockIdx.x * 256 + threadIdx.x;   // 0..16777215
  const int rt = u >> 7, c4 = u & 127;
  const int seg = rt >> 3;
  const int idx = idxf[seg];
  q4[u] = emb4[idx * 128 + c4];
  if(c4 == 0) idxo[rt] = (float)idx;
}

extern "C" void kernel_launch(void* const* d_in, const int* in_sizes, int n_in,
                              void* d_out, int out_size, void* d_ws, size_t ws_size,
                              hipStream_t stream){
  const float* x   = (const float*)d_in[0];
  const float* emb = (const float*)d_in[1];
  const float* wb  = (const float*)d_in[2];
  const float* bb  = (const float*)d_in[3];
  float* out = (float*)d_out;

  // small workspace fields
  char* ws = (char*)d_ws;
  int*    cnt   = (int*)(ws + 0);
  double* part  = (double*)(ws + 64);       // 4096 doubles
  float*  enorm = (float*)(ws + 32832);     // 8192 floats
  int*    idxf  = (int*)(ws + 65600);       // 16384 ints

  // big scratch inside the quantized_out region (overwritten last by k_expand)
  float*          pooled  = (float*)d_out;                                   // 32 MB @ 0
  unsigned int*   cand    = (unsigned int*)((char*)d_out + (48ull  << 20));  // 16 MB @ 48M
  unsigned short* pooledh = (unsigned short*)((char*)d_out + (80ull << 20)); // 16 MB @ 80M
  unsigned short* embh    = (unsigned short*)((char*)d_out + (100ull<< 20)); //  8 MB @ 100M

  float* bnd   = out + BND_OFF;
  float* idxo  = out + IDX_OFF;
  float* lossp = out + LOSS_OFF;

  hipLaunchKernelGGL(k_init,     dim3(1),     dim3(64),  0, stream, cnt);
  hipLaunchKernelGGL(k_embnorm,  dim3(2048),  dim3(256), 0, stream, (const float4*)emb, enorm, embh);
  hipLaunchKernelGGL(k_boundary, dim3(1024),  dim3(256), 0, stream, (const float4*)x, (const float4*)wb, bb, bnd, cnt);
  hipLaunchKernelGGL(k_pool,     dim3(8192),  dim3(256), 0, stream, (const float4*)x, (float4*)pooled, pooledh);
  hipLaunchKernelGGL(k_distx,    dim3(8192),  dim3(256), 0, stream, pooledh, embh, enorm, cand);
  hipLaunchKernelGGL(k_fixup,    dim3(4096),  dim3(256), 0, stream, pooled, emb, cand, idxf, part);
  hipLaunchKernelGGL(k_loss,     dim3(1),     dim3(256), 0, stream, part, cnt, lossp);
  hipLaunchKernelGGL(k_expand,   dim3(65536), dim3(256), 0, stream, (const float4*)emb, idxf, (float4*)d_out, idxo);
}

// Round 3
// 702.010 us; speedup vs baseline: 3.6537x; 1.0688x over previous
//
#include <hip/hip_runtime.h>

#define B_    16
#define T_    8192
#define D_    512
#define K_    8192
#define S_    1024
#define N_    16384      // B_*S_
#define NBT   131072     // B_*T_

// d_out float offsets
#define LOSS_OFF 67108864
#define IDX_OFF  67108865
#define BND_OFF  67239937

typedef __bf16 bf16x8 __attribute__((ext_vector_type(8)));
typedef float  f32x4  __attribute__((ext_vector_type(4)));

__device__ __forceinline__ unsigned int fsort(float f){
  unsigned int u = __float_as_uint(f);
  return (u & 0x80000000u) ? ~u : (u | 0x80000000u);
}
__device__ __forceinline__ float funsort(unsigned int su){
  unsigned int u = (su & 0x80000000u) ? (su ^ 0x80000000u) : ~su;
  return __uint_as_float(u);
}
__device__ __forceinline__ unsigned short f2bf(float f){
  unsigned int u = __float_as_uint(f);
  return (unsigned short)((u + 0x7fffu + ((u >> 16) & 1u)) >> 16);
}
__device__ __forceinline__ void gload16(const void* g, void* l){
  __builtin_amdgcn_global_load_lds((const __attribute__((address_space(1))) void*)g,
                                   (__attribute__((address_space(3))) void*)l, 16, 0, 0);
}

__global__ void k_init(int* cnt){
  if(threadIdx.x == 0 && blockIdx.x == 0) *cnt = 0;
}

// |emb_k|^2 (one wave per codebook row) + bf16 copy of emb
__global__ void k_embnorm(const float4* __restrict__ emb4, float* __restrict__ enorm,
                          unsigned short* __restrict__ embh){
  const int wid  = (blockIdx.x * blockDim.x + threadIdx.x) >> 6;   // 0..8191
  const int lane = threadIdx.x & 63;
  float4 a = emb4[wid * 128 + (lane << 1)];
  float4 b = emb4[wid * 128 + (lane << 1) + 1];
  float s = a.x*a.x + a.y*a.y + a.z*a.z + a.w*a.w
          + b.x*b.x + b.y*b.y + b.z*b.z + b.w*b.w;
  #pragma unroll
  for(int off = 32; off; off >>= 1) s += __shfl_xor(s, off);
  if(lane == 0) enorm[wid] = s;
  unsigned short* dst = embh + ((size_t)wid << 9) + (lane << 3);
  *(ushort4*)(dst)     = make_ushort4(f2bf(a.x), f2bf(a.y), f2bf(a.z), f2bf(a.w));
  *(ushort4*)(dst + 4) = make_ushort4(f2bf(b.x), f2bf(b.y), f2bf(b.z), f2bf(b.w));
}

// Fused: boundary (fp64 dot, parallel over 128 lanes) + mean-pool + bf16 convert.
// One block = 32 t-rows = 4 segments; reads x exactly once.
__launch_bounds__(256)
__global__ void k_prep(const float4* __restrict__ x4, const float4* __restrict__ wb4,
                       const float* __restrict__ bb, float4* __restrict__ pooled4,
                       unsigned short* __restrict__ pooledh, float* __restrict__ bnd,
                       int* __restrict__ cnt){
  __shared__ double ld[4][8][8];          // [seg_l][row_l][16-lane group]
  const int tid  = threadIdx.x;
  const int row0 = blockIdx.x << 5;       // first global t-row of this block
  const double bbv = (double)bb[0];
  #pragma unroll
  for(int it = 0; it < 2; it++){
    const int slot  = (it << 8) + tid;    // 0..511 = (seg_l:4) x (c4:128)
    const int seg_l = slot >> 7;
    const int c4    = slot & 127;
    const float4 w  = wb4[c4];
    const float4* src = x4 + ((size_t)(row0 + (seg_l << 3)) * 128 + c4);
    float4 acc = src[0];
    double p[8];
    p[0] = (double)acc.x*w.x + (double)acc.y*w.y + (double)acc.z*w.z + (double)acc.w*w.w;
    #pragma unroll
    for(int t = 1; t < 8; t++){
      const float4 v = src[(size_t)t * 128];
      acc.x += v.x; acc.y += v.y; acc.z += v.z; acc.w += v.w;
      p[t] = (double)v.x*w.x + (double)v.y*w.y + (double)v.z*w.z + (double)v.w*w.w;
    }
    acc.x *= 0.125f; acc.y *= 0.125f; acc.z *= 0.125f; acc.w *= 0.125f;
    const int u = ((blockIdx.x << 2) + seg_l) * 128 + c4;
    pooled4[u] = acc;
    *(ushort4*)(pooledh + ((size_t)u << 2)) =
        make_ushort4(f2bf(acc.x), f2bf(acc.y), f2bf(acc.z), f2bf(acc.w));
    // reduce partial dots over 16-lane groups (xor offsets 1,2,4,8)
    #pragma unroll
    for(int t = 0; t < 8; t++){
      #pragma unroll
      for(int off = 1; off < 16; off <<= 1) p[t] += __shfl_xor(p[t], off);
    }
    if((c4 & 15) == 0){
      #pragma unroll
      for(int t = 0; t < 8; t++) ld[seg_l][t][c4 >> 4] = p[t];
    }
  }
  __syncthreads();
  if(tid < 32){
    const double* q = ld[tid >> 3][tid & 7];
    double s = bbv;
    #pragma unroll
    for(int h = 0; h < 8; h++) s += q[h];
    const bool f = s > 0.0;
    bnd[row0 + tid] = f ? 1.0f : 0.0f;
    const unsigned long long m = __ballot(f);
    if(tid == 0) atomicAdd(cnt, (int)__popcll(m));
  }
}

// bf16 MFMA distance GEMM: 128x128 tile, BK=32, global_load_lds staging.
// Emits top-2 packed keys (19-bit trunc sorted dist | 13-bit col) per (row, 16-col group).
__launch_bounds__(256, 4)
__global__ void k_distx(const unsigned short* __restrict__ Ah,
                        const unsigned short* __restrict__ Bh,
                        const float* __restrict__ enorm,
                        unsigned long long* __restrict__ cand64){
  __shared__ __align__(16) unsigned short sA[4096];   // [128][32] bf16
  __shared__ __align__(16) unsigned short sB[4096];
  const int tid  = threadIdx.x;
  const int w    = tid >> 6, lane = tid & 63;
  const int wm   = w >> 1,  wn   = w & 1;
  const int c    = lane & 15, q  = lane >> 4;

  // supertile: 8 row-tiles x 64 col-tiles per 512-block group (L2/LLC locality)
  const int bid   = blockIdx.x;
  const int st    = bid >> 9;
  const int loc   = bid & 511;
  const int row_t = (st << 3) + (loc & 7);   // 0..127
  const int col_t = loc >> 3;                // 0..63
  const int rowbase = row_t << 7;
  const int colbase = col_t << 7;

  f32x4 acc[4][4];
  #pragma unroll
  for(int i = 0; i < 4; i++)
    #pragma unroll
    for(int j = 0; j < 4; j++) acc[i][j] = (f32x4){0.f, 0.f, 0.f, 0.f};

  const int sr  = lane >> 2;            // staging row within 16-row chunk
  const int skc = (lane & 3) << 3;      // staging k offset (elements)

  const unsigned short* Ap0 = Ah + (size_t)(rowbase + w*32 + sr)      * 512 + skc;
  const unsigned short* Ap1 = Ah + (size_t)(rowbase + w*32 + 16 + sr) * 512 + skc;
  const unsigned short* Bp0 = Bh + (size_t)(colbase + w*32 + sr)      * 512 + skc;
  const unsigned short* Bp1 = Bh + (size_t)(colbase + w*32 + 16 + sr) * 512 + skc;
  unsigned short* lA0 = &sA[(w*32)      * 32];
  unsigned short* lA1 = &sA[(w*32 + 16) * 32];
  unsigned short* lB0 = &sB[(w*32)      * 32];
  unsigned short* lB1 = &sB[(w*32 + 16) * 32];

  for(int kb = 0; kb < 512; kb += 32){
    gload16(Ap0 + kb, lA0);
    gload16(Ap1 + kb, lA1);
    gload16(Bp0 + kb, lB0);
    gload16(Bp1 + kb, lB1);
    __syncthreads();
    bf16x8 af[4], bg[4];
    #pragma unroll
    for(int i = 0; i < 4; i++) af[i] = *(const bf16x8*)&sA[(wm*64 + i*16 + c)*32 + q*8];
    #pragma unroll
    for(int j = 0; j < 4; j++) bg[j] = *(const bf16x8*)&sB[(wn*64 + j*16 + c)*32 + q*8];
    #pragma unroll
    for(int i = 0; i < 4; i++)
      #pragma unroll
      for(int j = 0; j < 4; j++)
        acc[i][j] = __builtin_amdgcn_mfma_f32_16x16x32_bf16(af[i], bg[j], acc[i][j], 0, 0, 0);
    __syncthreads();
  }

  // epilogue: dist = enorm - 2*dot; in-thread top-2 over 4 j-cols, then 2-step
  // butterfly -> top-2 per 16-col group; quarter-lanes store packed u64.
  float en[4];
  #pragma unroll
  for(int j = 0; j < 4; j++) en[j] = enorm[colbase + wn*64 + j*16 + c];

  #pragma unroll
  for(int i = 0; i < 4; i++){
    #pragma unroll
    for(int r = 0; r < 4; r++){
      unsigned int k1 = 0xffffffffu, k2 = 0xffffffffu;
      #pragma unroll
      for(int j = 0; j < 4; j++){
        const float d = fmaf(-2.0f, acc[i][j][r], en[j]);
        const unsigned int col = (unsigned int)(colbase + wn*64 + j*16 + c);
        const unsigned int key = (fsort(d) & 0xffffe000u) | col;
        if(key < k1){ k2 = k1; k1 = key; } else if(key < k2){ k2 = key; }
      }
      #pragma unroll
      for(int off = 1; off < 4; off <<= 1){
        const unsigned int o1 = __shfl_xor(k1, off);
        const unsigned int o2 = __shfl_xor(k2, off);
        if(o1 < k1){ k2 = min(k1, o2); k1 = o1; }
        else       { k2 = min(k2, o1); }
      }
      if((c & 3) == 0){
        const int row = rowbase + wm*64 + i*16 + (q << 2) + r;
        const int g   = (col_t << 3) + (wn << 2) + (c >> 2);   // 0..511
        cand64[(size_t)row * 512 + g] = ((unsigned long long)k2 << 32) | k1;
      }
    }
  }
}

// fp64 rescore of candidates within margin of min -> exact argmin + per-row loss term
__launch_bounds__(256)
__global__ void k_fixup(const float* __restrict__ pooled, const float* __restrict__ emb,
                        const unsigned int* __restrict__ cand,
                        int* __restrict__ idxf, double* __restrict__ part){
  const int lane = threadIdx.x & 63, wv = threadIdx.x >> 6;
  const int row = (blockIdx.x << 2) + wv;
  const uint4* cr = (const uint4*)(cand + ((size_t)row << 10));
  unsigned int ks[16];
  #pragma unroll
  for(int m = 0; m < 4; m++){
    const uint4 v = cr[m*64 + lane];
    ks[m*4+0] = v.x; ks[m*4+1] = v.y; ks[m*4+2] = v.z; ks[m*4+3] = v.w;
  }
  unsigned int mn = 0xffffffffu;
  #pragma unroll
  for(int g = 0; g < 16; g++) mn = min(mn, ks[g]);
  #pragma unroll
  for(int off = 32; off; off >>= 1) mn = min(mn, (unsigned int)__shfl_xor(mn, off));
  const float thr = funsort(mn & 0xffffe000u) + 0.01f;   // covers bf16 + key-trunc error

  double bestd = 1e300; int besti = 0x7fffffff;
  const float4* p4 = (const float4*)(pooled + ((size_t)row << 9));
  const float4 pa = p4[lane << 1], pb = p4[(lane << 1) + 1];
  #pragma unroll
  for(int g = 0; g < 16; g++){
    const bool flag = funsort(ks[g] & 0xffffe000u) <= thr;
    unsigned long long mask = __ballot(flag);
    while(mask){
      const int l = __ffsll(mask) - 1;
      mask &= mask - 1;
      const int code = (int)(__shfl(ks[g], l) & 0x1fffu);
      const float4* e4 = (const float4*)(emb + ((size_t)code << 9));
      const float4 ea = e4[lane << 1], eb = e4[(lane << 1) + 1];
      double s = 0.0, d;
      d = (double)pa.x - ea.x; s += d * d;  d = (double)pa.y - ea.y; s += d * d;
      d = (double)pa.z - ea.z; s += d * d;  d = (double)pa.w - ea.w; s += d * d;
      d = (double)pb.x - eb.x; s += d * d;  d = (double)pb.y - eb.y; s += d * d;
      d = (double)pb.z - eb.z; s += d * d;  d = (double)pb.w - eb.w; s += d * d;
      #pragma unroll
      for(int off = 32; off; off >>= 1) s += __shfl_xor(s, off);
      if(s < bestd || (s == bestd && code < besti)){ bestd = s; besti = code; }
    }
  }
  __shared__ double se[4];
  if(lane == 0){ idxf[row] = besti; se[wv] = bestd; }
  __syncthreads();
  if(threadIdx.x == 0) part[blockIdx.x] = se[0] + se[1] + se[2] + se[3];
}

__global__ void k_loss(const double* __restrict__ part, const int* __restrict__ cnt,
                       float* __restrict__ out_loss){
  const int tid = threadIdx.x;
  double s = 0.0;
  for(int i = tid; i < 4096; i += 256) s += part[i];
  #pragma unroll
  for(int off = 32; off; off >>= 1) s += __shfl_xor(s, off);
  __shared__ double sb[4];
  if((tid & 63) == 0) sb[tid >> 6] = s;
  __syncthreads();
  if(tid == 0){
    const double e  = sb[0] + sb[1] + sb[2] + sb[3];
    const double el = e / (double)((size_t)N_ * 512);
    const double bm = (double)(*cnt) / 131072.0 - 0.125;
    const double loss = 0.25 * el + 0.01 * bm * bm;
    *out_loss = (float)loss;
  }
}

// expand codes over SPAN: one wave per segment, 16 coalesced 1KB stores
__launch_bounds__(256)
__global__ void k_expand(const float4* __restrict__ emb4, const int* __restrict__ idxf,
                         float4* __restrict__ q4, float* __restrict__ idxo){
  const int lane = threadIdx.x & 63, wv = threadIdx.x >> 6;
  const int seg = (blockIdx.x << 2) + wv;      // 0..16383
  const int idx = idxf[seg];
  const float4 a = emb4[idx * 128 + (lane << 1)];
  const float4 b = emb4[idx * 128 + (lane << 1) + 1];
  float4* dst = q4 + ((size_t)seg << 10);
  #pragma unroll
  for(int t = 0; t < 8; t++){
    dst[t * 128 + (lane << 1)]     = a;
    dst[t * 128 + (lane << 1) + 1] = b;
  }
  if(lane < 8) idxo[(seg << 3) + lane] = (float)idx;
}

extern "C" void kernel_launch(void* const* d_in, const int* in_sizes, int n_in,
                              void* d_out, int out_size, void* d_ws, size_t ws_size,
                              hipStream_t stream){
  const float* x   = (const float*)d_in[0];
  const float* emb = (const float*)d_in[1];
  const float* wb  = (const float*)d_in[2];
  const float* bb  = (const float*)d_in[3];
  float* out = (float*)d_out;

  // small workspace fields
  char* ws = (char*)d_ws;
  int*    cnt   = (int*)(ws + 0);
  double* part  = (double*)(ws + 64);       // 4096 doubles
  float*  enorm = (float*)(ws + 32832);     // 8192 floats
  int*    idxf  = (int*)(ws + 65600);       // 16384 ints

  // big scratch inside the quantized_out region (overwritten last by k_expand)
  float*              pooled  = (float*)d_out;                                        // 32 MB @ 0
  unsigned long long* cand64  = (unsigned long long*)((char*)d_out + (48ull  << 20)); // 64 MB @ 48M
  unsigned short*     pooledh = (unsigned short*)((char*)d_out + (112ull << 20));     // 16 MB @ 112M
  unsigned short*     embh    = (unsigned short*)((char*)d_out + (128ull << 20));     //  8 MB @ 128M

  float* bnd   = out + BND_OFF;
  float* idxo  = out + IDX_OFF;
  float* lossp = out + LOSS_OFF;

  hipLaunchKernelGGL(k_init,    dim3(1),     dim3(64),  0, stream, cnt);
  hipLaunchKernelGGL(k_embnorm, dim3(2048),  dim3(256), 0, stream, (const float4*)emb, enorm, embh);
  hipLaunchKernelGGL(k_prep,    dim3(4096),  dim3(256), 0, stream, (const float4*)x, (const float4*)wb,
                     bb, (float4*)pooled, pooledh, bnd, cnt);
  hipLaunchKernelGGL(k_distx,   dim3(8192),  dim3(256), 0, stream, pooledh, embh, enorm, cand64);
  hipLaunchKernelGGL(k_fixup,   dim3(4096),  dim3(256), 0, stream, pooled, emb, (const unsigned int*)cand64, idxf, part);
  hipLaunchKernelGGL(k_loss,    dim3(1),     dim3(256), 0, stream, part, cnt, lossp);
  hipLaunchKernelGGL(k_expand,  dim3(4096),  dim3(256), 0, stream, (const float4*)emb, idxf, (float4*)d_out, idxo);
}

// Round 4
// 697.278 us; speedup vs baseline: 3.6785x; 1.0068x over previous
//
#include <hip/hip_runtime.h>

#define B_    16
#define T_    8192
#define D_    512
#define K_    8192
#define S_    1024
#define N_    16384      // B_*S_
#define NBT   131072     // B_*T_

// d_out float offsets
#define LOSS_OFF 67108864
#define IDX_OFF  67108865
#define BND_OFF  67239937

typedef __bf16 bf16x8 __attribute__((ext_vector_type(8)));
typedef float  f32x4  __attribute__((ext_vector_type(4)));

__device__ __forceinline__ unsigned int fsort(float f){
  unsigned int u = __float_as_uint(f);
  return (u & 0x80000000u) ? ~u : (u | 0x80000000u);
}
__device__ __forceinline__ float funsort(unsigned int su){
  unsigned int u = (su & 0x80000000u) ? (su ^ 0x80000000u) : ~su;
  return __uint_as_float(u);
}
__device__ __forceinline__ unsigned short f2bf(float f){
  unsigned int u = __float_as_uint(f);
  return (unsigned short)((u + 0x7fffu + ((u >> 16) & 1u)) >> 16);
}
__device__ __forceinline__ void gload16(const void* g, void* l){
  __builtin_amdgcn_global_load_lds((const __attribute__((address_space(1))) void*)g,
                                   (__attribute__((address_space(3))) void*)l, 16, 0, 0);
}

// |emb_k|^2 (one wave per codebook row) + bf16 copy of emb; block 0 inits cnt
__global__ void k_embnorm(const float4* __restrict__ emb4, float* __restrict__ enorm,
                          unsigned short* __restrict__ embh, int* __restrict__ cnt){
  if(blockIdx.x == 0 && threadIdx.x == 0) *cnt = 0;
  const int wid  = (blockIdx.x * blockDim.x + threadIdx.x) >> 6;   // 0..8191
  const int lane = threadIdx.x & 63;
  float4 a = emb4[wid * 128 + (lane << 1)];
  float4 b = emb4[wid * 128 + (lane << 1) + 1];
  float s = a.x*a.x + a.y*a.y + a.z*a.z + a.w*a.w
          + b.x*b.x + b.y*b.y + b.z*b.z + b.w*b.w;
  #pragma unroll
  for(int off = 32; off; off >>= 1) s += __shfl_xor(s, off);
  if(lane == 0) enorm[wid] = s;
  unsigned short* dst = embh + ((size_t)wid << 9) + (lane << 3);
  *(ushort4*)(dst)     = make_ushort4(f2bf(a.x), f2bf(a.y), f2bf(a.z), f2bf(a.w));
  *(ushort4*)(dst + 4) = make_ushort4(f2bf(b.x), f2bf(b.y), f2bf(b.z), f2bf(b.w));
}

// Fused: boundary (fp64 dot, parallel over 128 lanes) + mean-pool + bf16 convert.
// One block = 32 t-rows = 4 segments; reads x exactly once.
__launch_bounds__(256)
__global__ void k_prep(const float4* __restrict__ x4, const float4* __restrict__ wb4,
                       const float* __restrict__ bb, float4* __restrict__ pooled4,
                       unsigned short* __restrict__ pooledh, float* __restrict__ bnd,
                       int* __restrict__ cnt){
  __shared__ double ld[4][8][8];          // [seg_l][row_l][16-lane group]
  const int tid  = threadIdx.x;
  const int row0 = blockIdx.x << 5;       // first global t-row of this block
  const double bbv = (double)bb[0];
  #pragma unroll
  for(int it = 0; it < 2; it++){
    const int slot  = (it << 8) + tid;    // 0..511 = (seg_l:4) x (c4:128)
    const int seg_l = slot >> 7;
    const int c4    = slot & 127;
    const float4 w  = wb4[c4];
    const float4* src = x4 + ((size_t)(row0 + (seg_l << 3)) * 128 + c4);
    float4 acc = src[0];
    double p[8];
    p[0] = (double)acc.x*w.x + (double)acc.y*w.y + (double)acc.z*w.z + (double)acc.w*w.w;
    #pragma unroll
    for(int t = 1; t < 8; t++){
      const float4 v = src[(size_t)t * 128];
      acc.x += v.x; acc.y += v.y; acc.z += v.z; acc.w += v.w;
      p[t] = (double)v.x*w.x + (double)v.y*w.y + (double)v.z*w.z + (double)v.w*w.w;
    }
    acc.x *= 0.125f; acc.y *= 0.125f; acc.z *= 0.125f; acc.w *= 0.125f;
    const int u = ((blockIdx.x << 2) + seg_l) * 128 + c4;
    pooled4[u] = acc;
    *(ushort4*)(pooledh + ((size_t)u << 2)) =
        make_ushort4(f2bf(acc.x), f2bf(acc.y), f2bf(acc.z), f2bf(acc.w));
    #pragma unroll
    for(int t = 0; t < 8; t++){
      #pragma unroll
      for(int off = 1; off < 16; off <<= 1) p[t] += __shfl_xor(p[t], off);
    }
    if((c4 & 15) == 0){
      #pragma unroll
      for(int t = 0; t < 8; t++) ld[seg_l][t][c4 >> 4] = p[t];
    }
  }
  __syncthreads();
  if(tid < 32){
    const double* q = ld[tid >> 3][tid & 7];
    double s = bbv;
    #pragma unroll
    for(int h = 0; h < 8; h++) s += q[h];
    const bool f = s > 0.0;
    bnd[row0 + tid] = f ? 1.0f : 0.0f;
    const unsigned long long m = __ballot(f);
    if(tid == 0) atomicAdd(cnt, (int)__popcll(m));
  }
}

// bf16 MFMA distance GEMM: 128x128 tile, BK=32, global_load_lds staging.
// XCD-aware block swizzle: bid%8 = XCD; each XCD owns a 16-row-tile slab (A 2MB)
// and sweeps col-tiles col-major (B ~1MB resident) -> per-XCD L2 working set ~3MB.
// Emits top-2 packed keys (19-bit trunc sorted dist | 13-bit col) per (row, 64-col half-tile).
__launch_bounds__(256, 4)
__global__ void k_distx(const unsigned short* __restrict__ Ah,
                        const unsigned short* __restrict__ Bh,
                        const float* __restrict__ enorm,
                        unsigned long long* __restrict__ cand64){
  __shared__ __align__(16) unsigned short sA[4096];   // [128][32] bf16
  __shared__ __align__(16) unsigned short sB[4096];
  const int tid  = threadIdx.x;
  const int w    = tid >> 6, lane = tid & 63;
  const int wm   = w >> 1,  wn   = w & 1;
  const int c    = lane & 15, q  = lane >> 4;

  const int bid   = blockIdx.x;
  const int xcd   = bid & 7;
  const int local = bid >> 3;                 // 0..1023 within XCD
  const int row_t = (xcd << 4) + (local & 15); // 0..127 (16-row slab per XCD)
  const int col_t = local >> 4;               // 0..63  (col-major sweep)
  const int rowbase = row_t << 7;
  const int colbase = col_t << 7;

  f32x4 acc[4][4];
  #pragma unroll
  for(int i = 0; i < 4; i++)
    #pragma unroll
    for(int j = 0; j < 4; j++) acc[i][j] = (f32x4){0.f, 0.f, 0.f, 0.f};

  const int sr  = lane >> 2;            // staging row within 16-row chunk
  const int skc = (lane & 3) << 3;      // staging k offset (elements)

  const unsigned short* Ap0 = Ah + (size_t)(rowbase + w*32 + sr)      * 512 + skc;
  const unsigned short* Ap1 = Ah + (size_t)(rowbase + w*32 + 16 + sr) * 512 + skc;
  const unsigned short* Bp0 = Bh + (size_t)(colbase + w*32 + sr)      * 512 + skc;
  const unsigned short* Bp1 = Bh + (size_t)(colbase + w*32 + 16 + sr) * 512 + skc;
  unsigned short* lA0 = &sA[(w*32)      * 32];
  unsigned short* lA1 = &sA[(w*32 + 16) * 32];
  unsigned short* lB0 = &sB[(w*32)      * 32];
  unsigned short* lB1 = &sB[(w*32 + 16) * 32];

  for(int kb = 0; kb < 512; kb += 32){
    gload16(Ap0 + kb, lA0);
    gload16(Ap1 + kb, lA1);
    gload16(Bp0 + kb, lB0);
    gload16(Bp1 + kb, lB1);
    __syncthreads();
    bf16x8 af[4], bg[4];
    #pragma unroll
    for(int i = 0; i < 4; i++) af[i] = *(const bf16x8*)&sA[(wm*64 + i*16 + c)*32 + q*8];
    #pragma unroll
    for(int j = 0; j < 4; j++) bg[j] = *(const bf16x8*)&sB[(wn*64 + j*16 + c)*32 + q*8];
    #pragma unroll
    for(int i = 0; i < 4; i++)
      #pragma unroll
      for(int j = 0; j < 4; j++)
        acc[i][j] = __builtin_amdgcn_mfma_f32_16x16x32_bf16(af[i], bg[j], acc[i][j], 0, 0, 0);
    __syncthreads();
  }

  // epilogue: dist = enorm - 2*dot; in-thread top-2 over 4 j-cols, 4-step
  // butterfly over 16 c-lanes -> top-2 per 64-col half-tile; lane c==0 stores u64.
  float en[4];
  #pragma unroll
  for(int j = 0; j < 4; j++) en[j] = enorm[colbase + wn*64 + j*16 + c];

  #pragma unroll
  for(int i = 0; i < 4; i++){
    #pragma unroll
    for(int r = 0; r < 4; r++){
      unsigned int k1 = 0xffffffffu, k2 = 0xffffffffu;
      #pragma unroll
      for(int j = 0; j < 4; j++){
        const float d = fmaf(-2.0f, acc[i][j][r], en[j]);
        const unsigned int col = (unsigned int)(colbase + wn*64 + j*16 + c);
        const unsigned int key = (fsort(d) & 0xffffe000u) | col;
        if(key < k1){ k2 = k1; k1 = key; } else if(key < k2){ k2 = key; }
      }
      #pragma unroll
      for(int off = 1; off < 16; off <<= 1){
        const unsigned int o1 = __shfl_xor(k1, off);
        const unsigned int o2 = __shfl_xor(k2, off);
        if(o1 < k1){ k2 = min(k1, o2); k1 = o1; }
        else       { k2 = min(k2, o1); }
      }
      if(c == 0){
        const int row = rowbase + wm*64 + i*16 + (q << 2) + r;
        cand64[((size_t)row << 7) + (col_t << 1) + wn] =
            ((unsigned long long)k2 << 32) | k1;
      }
    }
  }
}

// fp64 rescore of candidates within margin of min -> exact argmin + per-row loss term
__launch_bounds__(256)
__global__ void k_fixup(const float* __restrict__ pooled, const float* __restrict__ emb,
                        const unsigned long long* __restrict__ cand64,
                        int* __restrict__ idxf, double* __restrict__ part){
  const int lane = threadIdx.x & 63, wv = threadIdx.x >> 6;
  const int row = (blockIdx.x << 2) + wv;
  const ulonglong2* cr = (const ulonglong2*)(cand64 + ((size_t)row << 7));
  const ulonglong2 v = cr[lane];
  unsigned int ks[4];
  ks[0] = (unsigned int)v.x; ks[1] = (unsigned int)(v.x >> 32);
  ks[2] = (unsigned int)v.y; ks[3] = (unsigned int)(v.y >> 32);
  unsigned int mn = min(min(ks[0], ks[1]), min(ks[2], ks[3]));
  #pragma unroll
  for(int off = 32; off; off >>= 1) mn = min(mn, (unsigned int)__shfl_xor(mn, off));
  const float thr = funsort(mn & 0xffffe000u) + 0.01f;   // covers bf16 + key-trunc error

  double bestd = 1e300; int besti = 0x7fffffff;
  const float4* p4 = (const float4*)(pooled + ((size_t)row << 9));
  const float4 pa = p4[lane << 1], pb = p4[(lane << 1) + 1];
  #pragma unroll
  for(int g = 0; g < 4; g++){
    const bool flag = funsort(ks[g] & 0xffffe000u) <= thr;
    unsigned long long mask = __ballot(flag);
    while(mask){
      const int l = __ffsll(mask) - 1;
      mask &= mask - 1;
      const int code = (int)(__shfl(ks[g], l) & 0x1fffu);
      const float4* e4 = (const float4*)(emb + ((size_t)code << 9));
      const float4 ea = e4[lane << 1], eb = e4[(lane << 1) + 1];
      double s = 0.0, d;
      d = (double)pa.x - ea.x; s += d * d;  d = (double)pa.y - ea.y; s += d * d;
      d = (double)pa.z - ea.z; s += d * d;  d = (double)pa.w - ea.w; s += d * d;
      d = (double)pb.x - eb.x; s += d * d;  d = (double)pb.y - eb.y; s += d * d;
      d = (double)pb.z - eb.z; s += d * d;  d = (double)pb.w - eb.w; s += d * d;
      #pragma unroll
      for(int off = 32; off; off >>= 1) s += __shfl_xor(s, off);
      if(s < bestd || (s == bestd && code < besti)){ bestd = s; besti = code; }
    }
  }
  __shared__ double se[4];
  if(lane == 0){ idxf[row] = besti; se[wv] = bestd; }
  __syncthreads();
  if(threadIdx.x == 0) part[blockIdx.x] = se[0] + se[1] + se[2] + se[3];
}

__global__ void k_loss(const double* __restrict__ part, const int* __restrict__ cnt,
                       float* __restrict__ out_loss){
  const int tid = threadIdx.x;
  double s = 0.0;
  for(int i = tid; i < 4096; i += 256) s += part[i];
  #pragma unroll
  for(int off = 32; off; off >>= 1) s += __shfl_xor(s, off);
  __shared__ double sb[4];
  if((tid & 63) == 0) sb[tid >> 6] = s;
  __syncthreads();
  if(tid == 0){
    const double e  = sb[0] + sb[1] + sb[2] + sb[3];
    const double el = e / (double)((size_t)N_ * 512);
    const double bm = (double)(*cnt) / 131072.0 - 0.125;
    const double loss = 0.25 * el + 0.01 * bm * bm;
    *out_loss = (float)loss;
  }
}

// expand codes over SPAN: one wave per segment, 16 coalesced 1KB stores
__launch_bounds__(256)
__global__ void k_expand(const float4* __restrict__ emb4, const int* __restrict__ idxf,
                         float4* __restrict__ q4, float* __restrict__ idxo){
  const int lane = threadIdx.x & 63, wv = threadIdx.x >> 6;
  const int seg = (blockIdx.x << 2) + wv;      // 0..16383
  const int idx = idxf[seg];
  const float4 a = emb4[idx * 128 + (lane << 1)];
  const float4 b = emb4[idx * 128 + (lane << 1) + 1];
  float4* dst = q4 + ((size_t)seg << 10);
  #pragma unroll
  for(int t = 0; t < 8; t++){
    dst[t * 128 + (lane << 1)]     = a;
    dst[t * 128 + (lane << 1) + 1] = b;
  }
  if(lane < 8) idxo[(seg << 3) + lane] = (float)idx;
}

extern "C" void kernel_launch(void* const* d_in, const int* in_sizes, int n_in,
                              void* d_out, int out_size, void* d_ws, size_t ws_size,
                              hipStream_t stream){
  const float* x   = (const float*)d_in[0];
  const float* emb = (const float*)d_in[1];
  const float* wb  = (const float*)d_in[2];
  const float* bb  = (const float*)d_in[3];
  float* out = (float*)d_out;

  // small workspace fields
  char* ws = (char*)d_ws;
  int*    cnt   = (int*)(ws + 0);
  double* part  = (double*)(ws + 64);       // 4096 doubles
  float*  enorm = (float*)(ws + 32832);     // 8192 floats
  int*    idxf  = (int*)(ws + 65600);       // 16384 ints

  // big scratch inside the quantized_out region (overwritten last by k_expand)
  float*              pooled  = (float*)d_out;                                        // 32 MB @ 0
  unsigned long long* cand64  = (unsigned long long*)((char*)d_out + (48ull  << 20)); // 16 MB @ 48M
  unsigned short*     pooledh = (unsigned short*)((char*)d_out + (80ull  << 20));     // 16 MB @ 80M
  unsigned short*     embh    = (unsigned short*)((char*)d_out + (100ull << 20));     //  8 MB @ 100M

  float* bnd   = out + BND_OFF;
  float* idxo  = out + IDX_OFF;
  float* lossp = out + LOSS_OFF;

  hipLaunchKernelGGL(k_embnorm, dim3(2048),  dim3(256), 0, stream, (const float4*)emb, enorm, embh, cnt);
  hipLaunchKernelGGL(k_prep,    dim3(4096),  dim3(256), 0, stream, (const float4*)x, (const float4*)wb,
                     bb, (float4*)pooled, pooledh, bnd, cnt);
  hipLaunchKernelGGL(k_distx,   dim3(8192),  dim3(256), 0, stream, pooledh, embh, enorm, cand64);
  hipLaunchKernelGGL(k_fixup,   dim3(4096),  dim3(256), 0, stream, pooled, emb, cand64, idxf, part);
  hipLaunchKernelGGL(k_loss,    dim3(1),     dim3(256), 0, stream, part, cnt, lossp);
  hipLaunchKernelGGL(k_expand,  dim3(4096),  dim3(256), 0, stream, (const float4*)emb, idxf, (float4*)d_out, idxo);
}